// Round 1
// 336.469 us; speedup vs baseline: 1.0306x; 1.0306x over previous
//
#include <hip/hip_runtime.h>

// fp32 in/out; bf16 MFMA pipeline (threshold = 2% of ref absmax).
//
// Pipeline:
//  0) cvt_all : X, in_w, dep_w -> bf16; cvtT: out_w -> bf16 TRANSPOSED
//  1) bck  : bc = dep_w @ out_b + dep_b (fp32) ; also writes dep scores 1/2048
//  2) qkv  = Xb @ in_wb^T + in_b                     (MFMA GEMM, bf16 out)
//  3) Wc   = Wdb @ WoTb^T (bf16)  [projection fusion: enh = ctx@Wc^T + bc]
//  4) Vt   = transpose of V slices, with keys PERMUTED within each 32-block:
//     4-key chunk c -> position 2*(c&3)+(c>>2). This makes the attention
//     P C-frag -> A-frag transform the IDENTITY (zero shuffles): lane
//     (m16,quad) computes S^T for keys {quad*4+0..3, 16+quad*4+0..3}, and the
//     PV A-frag k-slot j is defined as key quad*4+(j&3)+16*(j>>2); V's B-frag
//     supplies the same permuted key order straight from LDS.
//  5) ctx  = flash-attention(qkv, Vt)  -- S^T = K.Q^T, lane-local softmax,
//     32 q/wave; K/V double-buffered via swizzled global_load_lds prefetch
//     (1 barrier/iter, loads in flight across compute). No bpermute/cndmask:
//     pfr = {pk0,pk1,pk2,pk3} directly (see 4).
//  6) enh  = ctx @ Wc^T + bc            (fp32 out -> d_out+4)

typedef __attribute__((ext_vector_type(8))) short short8;   // 8 x bf16
typedef __attribute__((ext_vector_type(4))) float float4v;  // MFMA C/D frag
typedef __attribute__((ext_vector_type(4))) int int4v;      // 16B copy
typedef __attribute__((ext_vector_type(2))) unsigned uint2v;

__device__ inline ushort f2bf(float f) {
  union { float f; unsigned u; } v; v.f = f;
  unsigned u = v.u;
  return (ushort)((u + 0x7FFFu + ((u >> 16) & 1u)) >> 16);  // RNE
}
__device__ inline float bf2f(ushort h) {
  union { unsigned u; float f; } v; v.u = ((unsigned)h) << 16;
  return v.f;
}
// RNE-pack two floats to bf16x2 (a -> low half).
__device__ inline unsigned pack2bf(float a, float b) {
  union { float f; unsigned u; } va, vb; va.f = a; vb.f = b;
  unsigned ua = va.u + 0x7FFFu + ((va.u >> 16) & 1u);
  unsigned ub = vb.u + 0x7FFFu + ((vb.u >> 16) & 1u);
  return __builtin_amdgcn_perm(ub, ua, 0x07060302);
}

// ---------------------------------------------------------------------------
// Fused fp32 -> bf16 conversion: X (8388608) | Wi (3145728) | Wd (1048576).
// ---------------------------------------------------------------------------
__global__ __launch_bounds__(256)
void cvt_all(const float* __restrict__ X, const float* __restrict__ Wi,
             const float* __restrict__ Wd,
             ushort* __restrict__ Xb, ushort* __restrict__ Wib,
             ushort* __restrict__ Wdb) {
  size_t i = ((size_t)blockIdx.x * 256 + threadIdx.x) * 8;
  const float* src; ushort* dst;
  if (i < 8388608)        { src = X  + i;              dst = Xb  + i; }
  else if (i < 11534336)  { src = Wi + (i - 8388608);  dst = Wib + (i - 8388608); }
  else                    { src = Wd + (i - 11534336); dst = Wdb + (i - 11534336); }
  float4v a = *(const float4v*)(src);
  float4v b = *(const float4v*)(src + 4);
  ushort o[8];
  o[0] = f2bf(a.x); o[1] = f2bf(a.y); o[2] = f2bf(a.z); o[3] = f2bf(a.w);
  o[4] = f2bf(b.x); o[5] = f2bf(b.y); o[6] = f2bf(b.z); o[7] = f2bf(b.w);
  *(int4v*)dst = *(const int4v*)o;
}

// ---------------------------------------------------------------------------
// Transposed cvt: WoT[c][r] = bf16(Wo[r][c]), 1024x1024. 64x64 LDS tile.
// ---------------------------------------------------------------------------
__global__ __launch_bounds__(256)
void cvtT(const float* __restrict__ Wo, ushort* __restrict__ WoT) {
  __shared__ ushort Ts[64 * 72];
  const int t = threadIdx.x;
  const int ct = blockIdx.x * 64, rt = blockIdx.y * 64;
#pragma unroll
  for (int i = 0; i < 4; i++) {
    const int row = i * 16 + (t >> 4), col4 = (t & 15) * 4;
    float4v v = *(const float4v*)(Wo + (size_t)(rt + row) * 1024 + ct + col4);
    ushort o[4] = {f2bf(v.x), f2bf(v.y), f2bf(v.z), f2bf(v.w)};
    *(uint2v*)(Ts + row * 72 + col4) = *(const uint2v*)o;
  }
  __syncthreads();
#pragma unroll
  for (int it = 0; it < 2; it++) {
    const int c = it * 256 + t;
    const int oc = c >> 3, r8 = (c & 7) * 8;
    ushort o[8];
#pragma unroll
    for (int j = 0; j < 8; j++) o[j] = Ts[(r8 + j) * 72 + oc];
    *(int4v*)(WoT + (size_t)(ct + oc) * 1024 + rt + r8) = *(const int4v*)o;
  }
}

// ---------------------------------------------------------------------------
// bc[row] = dot(Wd[row,:], bo) + bd[row]; rows 0..3 also emit dep scores.
// ---------------------------------------------------------------------------
__global__ __launch_bounds__(64)
void bck(const float* __restrict__ Wd, const float* __restrict__ bo,
         const float* __restrict__ bd, float* __restrict__ bc,
         float* __restrict__ dep) {
  const int row = blockIdx.x, lane = threadIdx.x;
  float s = 0.f;
#pragma unroll
  for (int i = 0; i < 4; i++) {
    const int j = i * 256 + lane * 4;
    float4v w = *(const float4v*)(Wd + (size_t)row * 1024 + j);
    float4v b = *(const float4v*)(bo + j);
    s += w.x * b.x + w.y * b.y + w.z * b.z + w.w * b.w;
  }
#pragma unroll
  for (int off = 1; off <= 32; off <<= 1) s += __shfl_xor(s, off);
  if (lane == 0) bc[row] = s + bd[row];
  if (row < 4 && lane == 1) dep[row] = 1.0f / 2048.0f;  // softmax rows sum to 1
}

// ---------------------------------------------------------------------------
// GEMM: C[M,N] = A[M,K] @ W[N,K]^T + bias[N]; A,W bf16, bias fp32 (nullable).
// 128x128 tile, BK=32, 4 waves x (64x64). m97 structure (global_load_lds w=16).
// ---------------------------------------------------------------------------
template <bool OUT_BF16>
__global__ __launch_bounds__(256, 2)
void gemm_bt(const ushort* __restrict__ A, const ushort* __restrict__ W,
             const float* __restrict__ bias, void* __restrict__ Cv,
             int M, int N, int K) {
  __shared__ ushort As[128 * 32];
  __shared__ ushort Bs[128 * 32];
  const int t = threadIdx.x;
  const int w = t >> 6;
  const int lane = t & 63;
  const int m16 = lane & 15, quad = lane >> 4;
  const int bx = blockIdx.x, by = blockIdx.y;
  const int warpRow = w >> 1, warpCol = w & 1;

  const int srow = t >> 2;
  const int scol = (t & 3) * 8;
  const ushort* Aptr = A + (size_t)(by * 128) * K;
  const ushort* Wptr = W + (size_t)(bx * 128) * K;

  float4v zero4 = {0.f, 0.f, 0.f, 0.f};
  float4v acc[4][4];
#pragma unroll
  for (int i = 0; i < 4; i++)
#pragma unroll
    for (int j = 0; j < 4; j++) acc[i][j] = zero4;

  for (int k0 = 0; k0 < K; k0 += 32) {
    __syncthreads();
#pragma unroll
    for (int r = 0; r < 2; r++) {
      const ushort* g = Aptr + (size_t)(r * 64 + srow) * K + (k0 + scol);
      __builtin_amdgcn_global_load_lds(
          (const __attribute__((address_space(1))) void*)g,
          (__attribute__((address_space(3))) void*)(As + r * 2048 + t * 8),
          16, 0, 0);
    }
#pragma unroll
    for (int r = 0; r < 2; r++) {
      const ushort* g = Wptr + (size_t)(r * 64 + srow) * K + (k0 + scol);
      __builtin_amdgcn_global_load_lds(
          (const __attribute__((address_space(1))) void*)g,
          (__attribute__((address_space(3))) void*)(Bs + r * 2048 + t * 8),
          16, 0, 0);
    }
    __syncthreads();

    short8 af[4], bf[4];
#pragma unroll
    for (int i = 0; i < 4; i++) {
      af[i] = *(const short8*)(As + (warpRow * 64 + i * 16 + m16) * 32 + quad * 8);
      bf[i] = *(const short8*)(Bs + (warpCol * 64 + i * 16 + m16) * 32 + quad * 8);
    }
#pragma unroll
    for (int i = 0; i < 4; i++)
#pragma unroll
      for (int j = 0; j < 4; j++)
        acc[i][j] = __builtin_amdgcn_mfma_f32_16x16x32_bf16(af[i], bf[j],
                                                            acc[i][j], 0, 0, 0);
  }

  const int crow_base = by * 128 + warpRow * 64;
  const int ccol_base = bx * 128 + warpCol * 64;
#pragma unroll
  for (int j = 0; j < 4; j++) {
    const int col = ccol_base + j * 16 + m16;
    const float bv = bias ? bias[col] : 0.0f;
#pragma unroll
    for (int i = 0; i < 4; i++) {
      const int row = crow_base + i * 16 + quad * 4;
#pragma unroll
      for (int r = 0; r < 4; r++) {
        const float v = acc[i][j][r] + bv;
        if constexpr (OUT_BF16)
          ((ushort*)Cv)[(size_t)(row + r) * N + col] = f2bf(v);
        else
          ((float*)Cv)[(size_t)(row + r) * N + col] = v;
      }
    }
  }
}

// ---------------------------------------------------------------------------
// V transpose: qkv V-slice [b, s, h*128+d] -> Vt[(b*8+h)*128 + d][s'] where
// s' permutes keys within each 32-block: 4-key chunk c -> 2*(c&3)+(c>>2).
// (Zero-shuffle PV: position chunks 0..7 hold key-chunks 0,4,1,5,2,6,3,7,
//  i.e. position p (0..31) holds key quad*4+(p&3)+16*((p>>2)&1), quad=p>>3.)
// ---------------------------------------------------------------------------
__global__ __launch_bounds__(256, 2)
void vtrans(const ushort* __restrict__ qkv, ushort* __restrict__ Vt) {
  __shared__ ushort Vs[64 * 136];
  const int t = threadIdx.x;
  const int st = blockIdx.x, h = blockIdx.y, b = blockIdx.z;
  const ushort* src = qkv + ((size_t)(b * 2048 + st * 64)) * 3072 + 2048 + h * 128;

#pragma unroll
  for (int it = 0; it < 4; it++) {
    const int c = it * 256 + t;
    const int row = c >> 4, col8 = (c & 15) * 8;
    int4v v = *(const int4v*)(src + (size_t)row * 3072 + col8);
    *(int4v*)(Vs + row * 136 + col8) = v;
  }
  __syncthreads();

  const int d = t >> 1, sh = (t & 1) * 32;
  unsigned pk[16];
#pragma unroll
  for (int k = 0; k < 16; k++) {
    unsigned lo = Vs[(sh + 2 * k) * 136 + d];
    unsigned hi = Vs[(sh + 2 * k + 1) * 136 + d];
    pk[k] = lo | (hi << 16);
  }
  ushort* dst = Vt + ((size_t)((b * 8 + h) * 128 + d)) * 2048 + st * 64 + sh;
#pragma unroll
  for (int m = 0; m < 8; m++) {
    // 4-key chunk m (keys sh+4m..+3) -> permuted position chunk 2*(m&3)+(m>>2)
    const int pos4 = ((m & 3) << 1) | (m >> 2);
    uint2v o;
    o.x = pk[2 * m];
    o.y = pk[2 * m + 1];
    *(uint2v*)(dst + pos4 * 4) = o;
  }
}

// ---------------------------------------------------------------------------
// Flash attention. 256 thr = 4 waves, 32 q/wave. S^T = K.Q^T (lane-local
// softmax, no max pass). K/V tiles double-buffered in LDS via swizzled
// global_load_lds (conflict-balanced frag reads, lane-linear DMA dest).
// One barrier per kt; prefetch of kt+1 is in flight across compute of kt.
// P C-frag -> A-frag is the IDENTITY under the permuted key labeling:
// lane (m16,quad) holds S^T for query m16 at keys {quad*4+r, 16+quad*4+r}
// (r=0..3); PV A-frag k-slot j := key quad*4+(j&3)+16*(j>>2), so
// pfr = {pk0,pk1,pk2,pk3} with no cross-lane movement. Vt is stored with
// the same key permutation (see vtrans), so the V B-frag read is unchanged
// in shape (8 contiguous permuted keys per 16B chunk).
// LDS = 2*16K (K) + 2*16K (V) = 64 KB -> 2 blocks/CU.
// ---------------------------------------------------------------------------
__global__ __launch_bounds__(256, 2)
void attn(const ushort* __restrict__ qkv, const ushort* __restrict__ Vt,
          ushort* __restrict__ ctx) {
  __shared__ ushort Ks[2][64 * 128];   // [key][d-chunk swizzled]
  __shared__ ushort Vsm[2][128 * 64];  // [d][key-chunk swizzled]
  const int t = threadIdx.x, w = t >> 6, lane = t & 63;
  const int m16 = lane & 15, quad = lane >> 4;
  const int qt = blockIdx.x, h = blockIdx.y, b = blockIdx.z;
  const int E3 = 3072;
  const size_t bbase = (size_t)b * 2048;

  const ushort* Qg = qkv + (bbase + qt * 128 + w * 32) * E3 + h * 128;
  const ushort* Kg = qkv + bbase * E3 + 1024 + h * 128;
  const ushort* Vg = Vt + (size_t)((b * 8 + h) * 128) * 2048;

  auto stage = [&](int kt, int buf) {
#pragma unroll
    for (int it = 0; it < 4; it++) {                 // K: 64 keys x 128 d
      const int c = it * 256 + t;
      const int row = c >> 4, cir = c & 15;
      const int j = (cir & 8) | ((cir ^ row) & 7);   // swizzled source chunk
      const ushort* g = Kg + (size_t)(kt * 64 + row) * E3 + j * 8;
      __builtin_amdgcn_global_load_lds(
          (const __attribute__((address_space(1))) void*)g,
          (__attribute__((address_space(3))) void*)(&Ks[buf][c * 8]), 16, 0, 0);
    }
#pragma unroll
    for (int it = 0; it < 4; it++) {                 // V^T: 128 d x 64 keys
      const int c = it * 256 + t;
      const int d = c >> 3, cir = c & 7;
      const int j = cir ^ (d & 7);
      const ushort* g = Vg + (size_t)d * 2048 + kt * 64 + j * 8;
      __builtin_amdgcn_global_load_lds(
          (const __attribute__((address_space(1))) void*)g,
          (__attribute__((address_space(3))) void*)(&Vsm[buf][c * 8]), 16, 0, 0);
    }
  };

  stage(0, 0);

  const float c1 = 0.08838834764831845f * 1.4426950408889634f;  // scale*log2e
  // Q B-frags (n=m16 query, k=quad*8+j), pre-scaled by c1.
  short8 qf[2][4];
#pragma unroll
  for (int g = 0; g < 2; g++)
#pragma unroll
    for (int ks = 0; ks < 4; ks++) {
      short8 raw = *(const short8*)(Qg + (size_t)(g * 16 + m16) * E3 + ks * 32 + quad * 8);
      short8 s;
#pragma unroll
      for (int j = 0; j < 8; j++) s[j] = (short)f2bf(bf2f((ushort)raw[j]) * c1);
      qf[g][ks] = s;
    }

  // Per-lane swizzled chunk slots (row-low-3 = m16&7 for both K and V reads).
  int kslot[4];
#pragma unroll
  for (int ks = 0; ks < 4; ks++) {
    const int j = ks * 4 + quad;
    kslot[ks] = (j & 8) | ((j ^ m16) & 7);
  }

  float4v zero4 = {0.f, 0.f, 0.f, 0.f};
  float4v Oacc[2][8];
#pragma unroll
  for (int g = 0; g < 2; g++)
#pragma unroll
    for (int dt = 0; dt < 8; dt++) Oacc[g][dt] = zero4;
  float lsum[2] = {0.f, 0.f};

  for (int kt = 0; kt < 32; kt++) {
    const int cur = kt & 1;
    __syncthreads();                       // drains prefetch of tile kt
    if (kt < 31) stage(kt + 1, cur ^ 1);   // in flight across this compute
    const ushort* Ksb = Ks[cur];
    const ushort* Vsb = Vsm[cur];

#pragma unroll
    for (int half = 0; half < 2; half++) {
      float4v st[2][2];
      st[0][0] = zero4; st[0][1] = zero4; st[1][0] = zero4; st[1][1] = zero4;
#pragma unroll
      for (int ks = 0; ks < 4; ks++) {
#pragma unroll
        for (int mt2 = 0; mt2 < 2; mt2++) {
          short8 kf = *(const short8*)(Ksb + ((half * 2 + mt2) * 16 + m16) * 128 +
                                       kslot[ks] * 8);
          st[0][mt2] = __builtin_amdgcn_mfma_f32_16x16x32_bf16(kf, qf[0][ks], st[0][mt2], 0, 0, 0);
          st[1][mt2] = __builtin_amdgcn_mfma_f32_16x16x32_bf16(kf, qf[1][ks], st[1][mt2], 0, 0, 0);
        }
      }
      short8 pfr[2];
#pragma unroll
      for (int g = 0; g < 2; g++) {
        unsigned pk[4];
#pragma unroll
        for (int mt2 = 0; mt2 < 2; mt2++) {
          float p0 = __builtin_exp2f(st[g][mt2][0]);
          float p1 = __builtin_exp2f(st[g][mt2][1]);
          float p2 = __builtin_exp2f(st[g][mt2][2]);
          float p3 = __builtin_exp2f(st[g][mt2][3]);
          lsum[g] += (p0 + p1) + (p2 + p3);
          pk[mt2 * 2]     = pack2bf(p0, p1);
          pk[mt2 * 2 + 1] = pack2bf(p2, p3);
        }
        // Zero-shuffle: lane already holds its own A-frag keys
        // {quad*4+0..3, 16+quad*4+0..3}; Vt is key-permuted to match.
        union { int4v i; short8 s; } pf;
        pf.i.x = (int)pk[0];
        pf.i.y = (int)pk[1];
        pf.i.z = (int)pk[2];
        pf.i.w = (int)pk[3];
        pfr[g] = pf.s;
      }
#pragma unroll
      for (int dt = 0; dt < 8; dt++) {
        const int vslot = (half * 4 + quad) ^ (m16 & 7);
        short8 vf = *(const short8*)(Vsb + (dt * 16 + m16) * 64 + vslot * 8);
        Oacc[0][dt] = __builtin_amdgcn_mfma_f32_16x16x32_bf16(pfr[0], vf, Oacc[0][dt], 0, 0, 0);
        Oacc[1][dt] = __builtin_amdgcn_mfma_f32_16x16x32_bf16(pfr[1], vf, Oacc[1][dt], 0, 0, 0);
      }
    }
  }

  // Epilogue: reduce l across quads (query = m16), transpose via per-wave
  // scratch in Ks[0] (all waves are past the final barrier; wave-internal DS).
#pragma unroll
  for (int g = 0; g < 2; g++) {
    float l = lsum[g];
    l += __shfl_xor(l, 16);
    l += __shfl_xor(l, 32);
    float* lf = (float*)(&Ks[0][w * 64]);
    lf[m16] = l;
    float linv[4];
#pragma unroll
    for (int r = 0; r < 4; r++) linv[r] = 1.0f / lf[quad * 4 + r];
#pragma unroll
    for (int r = 0; r < 4; r++) {
      const int row = qt * 128 + w * 32 + g * 16 + quad * 4 + r;
      ushort* crow = ctx + (bbase + row) * 1024 + h * 128;
#pragma unroll
      for (int dt = 0; dt < 8; dt++)
        crow[dt * 16 + m16] = f2bf(Oacc[g][dt][r] * linv[r]);
    }
  }
}

extern "C" void kernel_launch(void* const* d_in, const int* in_sizes, int n_in,
                              void* d_out, int out_size, void* d_ws, size_t ws_size,
                              hipStream_t stream) {
  const float* X  = (const float*)d_in[0];
  const float* Wi = (const float*)d_in[1];
  const float* bi = (const float*)d_in[2];
  const float* Wo = (const float*)d_in[3];
  const float* bo = (const float*)d_in[4];
  const float* Wd = (const float*)d_in[5];
  const float* bd = (const float*)d_in[6];
  float* out = (float*)d_out;

  ushort* p    = (ushort*)d_ws;
  ushort* Xb   = p; p += (size_t)8192 * 1024;   // 16.8MB; ctx reuses (post-qkv)
  ushort* Wib  = p; p += (size_t)3072 * 1024;   //  6.3MB; Wcb reuses (post-qkv)
  ushort* WoTb = p; p += (size_t)1024 * 1024;   //  2.1MB
  ushort* Wdb  = p; p += (size_t)1024 * 1024;   //  2.1MB
  ushort* qkv  = p; p += (size_t)8192 * 3072;   // 50.3MB
  ushort* Vt   = p; p += (size_t)4096 * 2048;   // 16.8MB
  float*  bc   = (float*)p;                     //  4KB   -> total 94.4MB
  ushort* ctx  = Xb;   // free after qkv GEMM consumed Xb
  ushort* Wcb  = Wib;  // free after qkv GEMM consumed Wib

  cvt_all<<<6144, 256, 0, stream>>>(X, Wi, Wd, Xb, Wib, Wdb);
  cvtT<<<dim3(16, 16), 256, 0, stream>>>(Wo, WoTb);
  bck<<<1024, 64, 0, stream>>>(Wd, bo, bd, bc, out);
  gemm_bt<true><<<dim3(24, 64), 256, 0, stream>>>(Xb, Wib, bi, qkv, 8192, 3072, 1024);
  gemm_bt<true><<<dim3(8, 8), 256, 0, stream>>>(Wdb, WoTb, nullptr, Wcb, 1024, 1024, 1024);
  vtrans<<<dim3(32, 8, 4), 256, 0, stream>>>(qkv, Vt);
  attn<<<dim3(16, 8, 4), 256, 0, stream>>>(qkv, Vt, ctx);
  gemm_bt<false><<<dim3(8, 64), 256, 0, stream>>>(ctx, Wcb, bc, out + 4, 8192, 1024, 1024);
}

// Round 2
// 300.231 us; speedup vs baseline: 1.1550x; 1.1207x over previous
//
#include <hip/hip_runtime.h>

// fp32 in/out; bf16 MFMA pipeline (threshold = 2% of ref absmax).
//
// Pipeline:
//  0) cvt_all : X, in_w, dep_w -> bf16; cvtT: out_w -> bf16 TRANSPOSED
//  1) bck  : bc = dep_w @ out_b + dep_b (fp32) ; also writes dep scores 1/2048
//  2) gemm_qkv : qkv(Q,K cols) = Xb @ in_wb^T + in_b  (MFMA GEMM, bf16 out)
//       - V cols (bx>=16) are written DIRECTLY to Vt, transposed with the
//         zero-shuffle key permutation baked in (vtrans kernel eliminated).
//       - blocks 1536..1599 (when workspace allows) compute Wc = Wdb @ WoTb^T
//         concurrently (hides the tiny 64-block GEMM under the big one).
//  3) ctx  = flash-attention(qkv, Vt)  -- S^T = K.Q^T, lane-local softmax,
//     32 q/wave; K/V double-buffered via swizzled global_load_lds prefetch
//     (1 barrier/iter). Zero-shuffle PV (P C-frag == A-frag under permuted
//     key labeling). Softmax pack via v_cvt_pk_bf16_f32 (1 instr vs 7).
//     s_setprio(1) around MFMA clusters (T5).
//  4) enh  = ctx @ Wc^T + bc            (fp32 out -> d_out+4)

typedef __attribute__((ext_vector_type(8))) short short8;   // 8 x bf16
typedef __attribute__((ext_vector_type(4))) float float4v;  // MFMA C/D frag
typedef __attribute__((ext_vector_type(4))) int int4v;      // 16B copy
typedef __attribute__((ext_vector_type(2))) unsigned uint2v;

__device__ inline ushort f2bf(float f) {
  union { float f; unsigned u; } v; v.f = f;
  unsigned u = v.u;
  return (ushort)((u + 0x7FFFu + ((u >> 16) & 1u)) >> 16);  // RNE
}
__device__ inline float bf2f(ushort h) {
  union { unsigned u; float f; } v; v.u = ((unsigned)h) << 16;
  return v.f;
}
// Single-instruction RNE pack of two floats to bf16x2 (lo -> low half).
__device__ inline unsigned cvtpk(float lo, float hi) {
  unsigned r;
  asm("v_cvt_pk_bf16_f32 %0, %1, %2" : "=v"(r) : "v"(lo), "v"(hi));
  return r;
}

// ---------------------------------------------------------------------------
// Fused fp32 -> bf16 conversion: X (8388608) | Wi (3145728) | Wd (1048576).
// ---------------------------------------------------------------------------
__global__ __launch_bounds__(256)
void cvt_all(const float* __restrict__ X, const float* __restrict__ Wi,
             const float* __restrict__ Wd,
             ushort* __restrict__ Xb, ushort* __restrict__ Wib,
             ushort* __restrict__ Wdb) {
  size_t i = ((size_t)blockIdx.x * 256 + threadIdx.x) * 8;
  const float* src; ushort* dst;
  if (i < 8388608)        { src = X  + i;              dst = Xb  + i; }
  else if (i < 11534336)  { src = Wi + (i - 8388608);  dst = Wib + (i - 8388608); }
  else                    { src = Wd + (i - 11534336); dst = Wdb + (i - 11534336); }
  float4v a = *(const float4v*)(src);
  float4v b = *(const float4v*)(src + 4);
  ushort o[8];
  o[0] = f2bf(a.x); o[1] = f2bf(a.y); o[2] = f2bf(a.z); o[3] = f2bf(a.w);
  o[4] = f2bf(b.x); o[5] = f2bf(b.y); o[6] = f2bf(b.z); o[7] = f2bf(b.w);
  *(int4v*)dst = *(const int4v*)o;
}

// ---------------------------------------------------------------------------
// Transposed cvt: WoT[c][r] = bf16(Wo[r][c]), 1024x1024. 64x64 LDS tile.
// ---------------------------------------------------------------------------
__global__ __launch_bounds__(256)
void cvtT(const float* __restrict__ Wo, ushort* __restrict__ WoT) {
  __shared__ ushort Ts[64 * 72];
  const int t = threadIdx.x;
  const int ct = blockIdx.x * 64, rt = blockIdx.y * 64;
#pragma unroll
  for (int i = 0; i < 4; i++) {
    const int row = i * 16 + (t >> 4), col4 = (t & 15) * 4;
    float4v v = *(const float4v*)(Wo + (size_t)(rt + row) * 1024 + ct + col4);
    ushort o[4] = {f2bf(v.x), f2bf(v.y), f2bf(v.z), f2bf(v.w)};
    *(uint2v*)(Ts + row * 72 + col4) = *(const uint2v*)o;
  }
  __syncthreads();
#pragma unroll
  for (int it = 0; it < 2; it++) {
    const int c = it * 256 + t;
    const int oc = c >> 3, r8 = (c & 7) * 8;
    ushort o[8];
#pragma unroll
    for (int j = 0; j < 8; j++) o[j] = Ts[(r8 + j) * 72 + oc];
    *(int4v*)(WoT + (size_t)(ct + oc) * 1024 + rt + r8) = *(const int4v*)o;
  }
}

// ---------------------------------------------------------------------------
// bc[row] = dot(Wd[row,:], bo) + bd[row]; rows 0..3 also emit dep scores.
// ---------------------------------------------------------------------------
__global__ __launch_bounds__(64)
void bck(const float* __restrict__ Wd, const float* __restrict__ bo,
         const float* __restrict__ bd, float* __restrict__ bc,
         float* __restrict__ dep) {
  const int row = blockIdx.x, lane = threadIdx.x;
  float s = 0.f;
#pragma unroll
  for (int i = 0; i < 4; i++) {
    const int j = i * 256 + lane * 4;
    float4v w = *(const float4v*)(Wd + (size_t)row * 1024 + j);
    float4v b = *(const float4v*)(bo + j);
    s += w.x * b.x + w.y * b.y + w.z * b.z + w.w * b.w;
  }
#pragma unroll
  for (int off = 1; off <= 32; off <<= 1) s += __shfl_xor(s, off);
  if (lane == 0) bc[row] = s + bd[row];
  if (row < 4 && lane == 1) dep[row] = 1.0f / 2048.0f;  // softmax rows sum to 1
}

// ---------------------------------------------------------------------------
// Generic GEMM: C[M,N] = A[M,K] @ W[N,K]^T + bias[N]; A,W bf16.
// 128x128 tile, BK=32, 4 waves x (64x64). m97 structure (global_load_lds w=16).
// ---------------------------------------------------------------------------
template <bool OUT_BF16>
__global__ __launch_bounds__(256, 2)
void gemm_bt(const ushort* __restrict__ A, const ushort* __restrict__ W,
             const float* __restrict__ bias, void* __restrict__ Cv,
             int M, int N, int K) {
  __shared__ ushort As[128 * 32];
  __shared__ ushort Bs[128 * 32];
  const int t = threadIdx.x;
  const int w = t >> 6;
  const int lane = t & 63;
  const int m16 = lane & 15, quad = lane >> 4;
  const int bx = blockIdx.x, by = blockIdx.y;
  const int warpRow = w >> 1, warpCol = w & 1;

  const int srow = t >> 2;
  const int scol = (t & 3) * 8;
  const ushort* Aptr = A + (size_t)(by * 128) * K;
  const ushort* Wptr = W + (size_t)(bx * 128) * K;

  float4v zero4 = {0.f, 0.f, 0.f, 0.f};
  float4v acc[4][4];
#pragma unroll
  for (int i = 0; i < 4; i++)
#pragma unroll
    for (int j = 0; j < 4; j++) acc[i][j] = zero4;

  for (int k0 = 0; k0 < K; k0 += 32) {
    __syncthreads();
#pragma unroll
    for (int r = 0; r < 2; r++) {
      const ushort* g = Aptr + (size_t)(r * 64 + srow) * K + (k0 + scol);
      __builtin_amdgcn_global_load_lds(
          (const __attribute__((address_space(1))) void*)g,
          (__attribute__((address_space(3))) void*)(As + r * 2048 + t * 8),
          16, 0, 0);
    }
#pragma unroll
    for (int r = 0; r < 2; r++) {
      const ushort* g = Wptr + (size_t)(r * 64 + srow) * K + (k0 + scol);
      __builtin_amdgcn_global_load_lds(
          (const __attribute__((address_space(1))) void*)g,
          (__attribute__((address_space(3))) void*)(Bs + r * 2048 + t * 8),
          16, 0, 0);
    }
    __syncthreads();

    short8 af[4], bf[4];
#pragma unroll
    for (int i = 0; i < 4; i++) {
      af[i] = *(const short8*)(As + (warpRow * 64 + i * 16 + m16) * 32 + quad * 8);
      bf[i] = *(const short8*)(Bs + (warpCol * 64 + i * 16 + m16) * 32 + quad * 8);
    }
#pragma unroll
    for (int i = 0; i < 4; i++)
#pragma unroll
      for (int j = 0; j < 4; j++)
        acc[i][j] = __builtin_amdgcn_mfma_f32_16x16x32_bf16(af[i], bf[j],
                                                            acc[i][j], 0, 0, 0);
  }

  const int crow_base = by * 128 + warpRow * 64;
  const int ccol_base = bx * 128 + warpCol * 64;
#pragma unroll
  for (int j = 0; j < 4; j++) {
    const int col = ccol_base + j * 16 + m16;
    const float bv = bias ? bias[col] : 0.0f;
#pragma unroll
    for (int i = 0; i < 4; i++) {
      const int row = crow_base + i * 16 + quad * 4;
#pragma unroll
      for (int r = 0; r < 4; r++) {
        const float v = acc[i][j][r] + bv;
        if constexpr (OUT_BF16)
          ((ushort*)Cv)[(size_t)(row + r) * N + col] = f2bf(v);
        else
          ((float*)Cv)[(size_t)(row + r) * N + col] = v;
      }
    }
  }
}

// ---------------------------------------------------------------------------
// Fused QKV GEMM. Blocks < 1536: qkv = Xb[8192,1024] @ Wib[3072,1024]^T + bi.
//   - bx < 16 : Q,K columns -> qkv (bf16, row-major, stride 3072)
//   - bx >= 16: V columns   -> Vt[(b*8+h)*128+d][key'] directly (transposed,
//     with the zero-shuffle key permutation: within each 32-key block, 4-key
//     chunk c goes to position 2*(c&3)+(c>>2)). The C-frag's 4 consecutive
//     rows (quad*4+r) form exactly one 4-key chunk -> one 8B store each.
// Blocks >= 1536 (optional): Wc = A2[1024,1024] @ W2[1024,1024]^T (bf16, no
//   bias) -> C2. Must NOT alias Wib (runs concurrently with qkv blocks).
// ---------------------------------------------------------------------------
__global__ __launch_bounds__(256, 2)
void gemm_qkv(const ushort* __restrict__ Xb, const ushort* __restrict__ Wib,
              const float* __restrict__ bi, ushort* __restrict__ qkv,
              ushort* __restrict__ Vt,
              const ushort* __restrict__ A2, const ushort* __restrict__ W2,
              ushort* __restrict__ C2) {
  __shared__ ushort As[128 * 32];
  __shared__ ushort Bs[128 * 32];
  const int t = threadIdx.x;
  const int w = t >> 6;
  const int lane = t & 63;
  const int m16 = lane & 15, quad = lane >> 4;
  const int bid = blockIdx.x;
  const bool second = bid >= 1536;
  int bx, by;
  const ushort *A, *W;
  if (!second) { bx = bid % 24; by = bid / 24; A = Xb; W = Wib; }
  else { const int b2 = bid - 1536; bx = b2 & 7; by = b2 >> 3; A = A2; W = W2; }
  const int warpRow = w >> 1, warpCol = w & 1;
  const int K = 1024;

  const int srow = t >> 2;
  const int scol = (t & 3) * 8;
  const ushort* Aptr = A + (size_t)(by * 128) * K;
  const ushort* Wptr = W + (size_t)(bx * 128) * K;

  float4v zero4 = {0.f, 0.f, 0.f, 0.f};
  float4v acc[4][4];
#pragma unroll
  for (int i = 0; i < 4; i++)
#pragma unroll
    for (int j = 0; j < 4; j++) acc[i][j] = zero4;

  for (int k0 = 0; k0 < K; k0 += 32) {
    __syncthreads();
#pragma unroll
    for (int r = 0; r < 2; r++) {
      const ushort* g = Aptr + (size_t)(r * 64 + srow) * K + (k0 + scol);
      __builtin_amdgcn_global_load_lds(
          (const __attribute__((address_space(1))) void*)g,
          (__attribute__((address_space(3))) void*)(As + r * 2048 + t * 8),
          16, 0, 0);
    }
#pragma unroll
    for (int r = 0; r < 2; r++) {
      const ushort* g = Wptr + (size_t)(r * 64 + srow) * K + (k0 + scol);
      __builtin_amdgcn_global_load_lds(
          (const __attribute__((address_space(1))) void*)g,
          (__attribute__((address_space(3))) void*)(Bs + r * 2048 + t * 8),
          16, 0, 0);
    }
    __syncthreads();

    short8 af[4], bf[4];
#pragma unroll
    for (int i = 0; i < 4; i++) {
      af[i] = *(const short8*)(As + (warpRow * 64 + i * 16 + m16) * 32 + quad * 8);
      bf[i] = *(const short8*)(Bs + (warpCol * 64 + i * 16 + m16) * 32 + quad * 8);
    }
#pragma unroll
    for (int i = 0; i < 4; i++)
#pragma unroll
      for (int j = 0; j < 4; j++)
        acc[i][j] = __builtin_amdgcn_mfma_f32_16x16x32_bf16(af[i], bf[j],
                                                            acc[i][j], 0, 0, 0);
  }

  const int crow_base = by * 128 + warpRow * 64;
  const int ccol_base = bx * 128 + warpCol * 64;

  if (second) {
    // Wc: bf16, no bias, N = 1024.
#pragma unroll
    for (int j = 0; j < 4; j++) {
      const int col = ccol_base + j * 16 + m16;
#pragma unroll
      for (int i = 0; i < 4; i++) {
        const int row = crow_base + i * 16 + quad * 4;
#pragma unroll
        for (int r = 0; r < 4; r++)
          C2[(size_t)(row + r) * 1024 + col] = f2bf(acc[i][j][r]);
      }
    }
  } else if (bx < 16) {
    // Q,K columns -> qkv (stride 3072).
#pragma unroll
    for (int j = 0; j < 4; j++) {
      const int col = ccol_base + j * 16 + m16;
      const float bv = bi[col];
#pragma unroll
      for (int i = 0; i < 4; i++) {
        const int row = crow_base + i * 16 + quad * 4;
#pragma unroll
        for (int r = 0; r < 4; r++)
          qkv[(size_t)(row + r) * 3072 + col] = f2bf(acc[i][j][r] + bv);
      }
    }
  } else {
    // V columns -> Vt transposed + key-permuted.
    const int b = by >> 4;  // batch (128-row tiles within 2048-row batches)
#pragma unroll
    for (int j = 0; j < 4; j++) {
      const int col = ccol_base + j * 16 + m16;   // 2048..3071
      const float bv = bi[col];
      const int vcol = col - 2048;
      const int h = vcol >> 7, d = vcol & 127;
      ushort* vrow = Vt + (size_t)((b * 8 + h) * 128 + d) * 2048;
#pragma unroll
      for (int i = 0; i < 4; i++) {
        // rows row..row+3 = keys s..s+3 (one 4-key chunk)
        const int pos = ((by & 15) << 7) + warpRow * 64 + ((i >> 1) << 5) +
                        (2 * quad + (i & 1)) * 4;
        uint2v o;
        o.x = cvtpk(acc[i][j][0] + bv, acc[i][j][1] + bv);
        o.y = cvtpk(acc[i][j][2] + bv, acc[i][j][3] + bv);
        *(uint2v*)(vrow + pos) = o;
      }
    }
  }
}

// ---------------------------------------------------------------------------
// Flash attention. 256 thr = 4 waves, 32 q/wave. S^T = K.Q^T (lane-local
// softmax, no max pass). K/V tiles double-buffered in LDS via swizzled
// global_load_lds (conflict-balanced frag reads, lane-linear DMA dest).
// One barrier per kt; prefetch of kt+1 is in flight across compute of kt.
// Zero-shuffle PV: lane (m16,quad) holds S^T for query m16 at keys
// {quad*4+r, 16+quad*4+r}; PV A-frag k-slot j := key quad*4+(j&3)+16*(j>>2);
// Vt stores the matching key permutation, so pfr = packed P directly.
// Softmax pack: v_cvt_pk_bf16_f32 (1 instr). setprio(1) around MFMA (T5).
// LDS = 2*16K (K) + 2*16K (V) = 64 KB -> 2 blocks/CU.
// ---------------------------------------------------------------------------
__global__ __launch_bounds__(256, 2)
void attn(const ushort* __restrict__ qkv, const ushort* __restrict__ Vt,
          ushort* __restrict__ ctx) {
  __shared__ ushort Ks[2][64 * 128];   // [key][d-chunk swizzled]
  __shared__ ushort Vsm[2][128 * 64];  // [d][key-chunk swizzled]
  const int t = threadIdx.x, w = t >> 6, lane = t & 63;
  const int m16 = lane & 15, quad = lane >> 4;
  const int qt = blockIdx.x, h = blockIdx.y, b = blockIdx.z;
  const int E3 = 3072;
  const size_t bbase = (size_t)b * 2048;

  const ushort* Qg = qkv + (bbase + qt * 128 + w * 32) * E3 + h * 128;
  const ushort* Kg = qkv + bbase * E3 + 1024 + h * 128;
  const ushort* Vg = Vt + (size_t)((b * 8 + h) * 128) * 2048;

  auto stage = [&](int kt, int buf) {
#pragma unroll
    for (int it = 0; it < 4; it++) {                 // K: 64 keys x 128 d
      const int c = it * 256 + t;
      const int row = c >> 4, cir = c & 15;
      const int j = (cir & 8) | ((cir ^ row) & 7);   // swizzled source chunk
      const ushort* g = Kg + (size_t)(kt * 64 + row) * E3 + j * 8;
      __builtin_amdgcn_global_load_lds(
          (const __attribute__((address_space(1))) void*)g,
          (__attribute__((address_space(3))) void*)(&Ks[buf][c * 8]), 16, 0, 0);
    }
#pragma unroll
    for (int it = 0; it < 4; it++) {                 // V^T: 128 d x 64 keys
      const int c = it * 256 + t;
      const int d = c >> 3, cir = c & 7;
      const int j = cir ^ (d & 7);
      const ushort* g = Vg + (size_t)d * 2048 + kt * 64 + j * 8;
      __builtin_amdgcn_global_load_lds(
          (const __attribute__((address_space(1))) void*)g,
          (__attribute__((address_space(3))) void*)(&Vsm[buf][c * 8]), 16, 0, 0);
    }
  };

  stage(0, 0);

  const float c1 = 0.08838834764831845f * 1.4426950408889634f;  // scale*log2e
  // Q B-frags (n=m16 query, k=quad*8+j), pre-scaled by c1.
  short8 qf[2][4];
#pragma unroll
  for (int g = 0; g < 2; g++)
#pragma unroll
    for (int ks = 0; ks < 4; ks++) {
      short8 raw = *(const short8*)(Qg + (size_t)(g * 16 + m16) * E3 + ks * 32 + quad * 8);
      short8 s;
#pragma unroll
      for (int j = 0; j < 8; j++) s[j] = (short)f2bf(bf2f((ushort)raw[j]) * c1);
      qf[g][ks] = s;
    }

  // Per-lane swizzled chunk slots (row-low-3 = m16&7 for both K and V reads).
  int kslot[4];
#pragma unroll
  for (int ks = 0; ks < 4; ks++) {
    const int j = ks * 4 + quad;
    kslot[ks] = (j & 8) | ((j ^ m16) & 7);
  }

  float4v zero4 = {0.f, 0.f, 0.f, 0.f};
  float4v Oacc[2][8];
#pragma unroll
  for (int g = 0; g < 2; g++)
#pragma unroll
    for (int dt = 0; dt < 8; dt++) Oacc[g][dt] = zero4;
  float lsum[2] = {0.f, 0.f};

  for (int kt = 0; kt < 32; kt++) {
    const int cur = kt & 1;
    __syncthreads();                       // drains prefetch of tile kt
    if (kt < 31) stage(kt + 1, cur ^ 1);   // in flight across this compute
    const ushort* Ksb = Ks[cur];
    const ushort* Vsb = Vsm[cur];

#pragma unroll
    for (int half = 0; half < 2; half++) {
      float4v st[2][2];
      st[0][0] = zero4; st[0][1] = zero4; st[1][0] = zero4; st[1][1] = zero4;
      __builtin_amdgcn_s_setprio(1);
#pragma unroll
      for (int ks = 0; ks < 4; ks++) {
#pragma unroll
        for (int mt2 = 0; mt2 < 2; mt2++) {
          short8 kf = *(const short8*)(Ksb + ((half * 2 + mt2) * 16 + m16) * 128 +
                                       kslot[ks] * 8);
          st[0][mt2] = __builtin_amdgcn_mfma_f32_16x16x32_bf16(kf, qf[0][ks], st[0][mt2], 0, 0, 0);
          st[1][mt2] = __builtin_amdgcn_mfma_f32_16x16x32_bf16(kf, qf[1][ks], st[1][mt2], 0, 0, 0);
        }
      }
      __builtin_amdgcn_s_setprio(0);
      short8 pfr[2];
#pragma unroll
      for (int g = 0; g < 2; g++) {
        unsigned pk[4];
#pragma unroll
        for (int mt2 = 0; mt2 < 2; mt2++) {
          float p0 = __builtin_exp2f(st[g][mt2][0]);
          float p1 = __builtin_exp2f(st[g][mt2][1]);
          float p2 = __builtin_exp2f(st[g][mt2][2]);
          float p3 = __builtin_exp2f(st[g][mt2][3]);
          lsum[g] += (p0 + p1) + (p2 + p3);
          pk[mt2 * 2]     = cvtpk(p0, p1);
          pk[mt2 * 2 + 1] = cvtpk(p2, p3);
        }
        // Zero-shuffle: lane already holds its own A-frag keys
        // {quad*4+0..3, 16+quad*4+0..3}; Vt is key-permuted to match.
        union { int4v i; short8 s; } pf;
        pf.i.x = (int)pk[0];
        pf.i.y = (int)pk[1];
        pf.i.z = (int)pk[2];
        pf.i.w = (int)pk[3];
        pfr[g] = pf.s;
      }
      __builtin_amdgcn_s_setprio(1);
#pragma unroll
      for (int dt = 0; dt < 8; dt++) {
        const int vslot = (half * 4 + quad) ^ (m16 & 7);
        short8 vf = *(const short8*)(Vsb + (dt * 16 + m16) * 64 + vslot * 8);
        Oacc[0][dt] = __builtin_amdgcn_mfma_f32_16x16x32_bf16(pfr[0], vf, Oacc[0][dt], 0, 0, 0);
        Oacc[1][dt] = __builtin_amdgcn_mfma_f32_16x16x32_bf16(pfr[1], vf, Oacc[1][dt], 0, 0, 0);
      }
      __builtin_amdgcn_s_setprio(0);
    }
  }

  // Epilogue: reduce l across quads (query = m16), transpose via per-wave
  // scratch in Ks[0] (all waves are past the final barrier; wave-internal DS).
#pragma unroll
  for (int g = 0; g < 2; g++) {
    float l = lsum[g];
    l += __shfl_xor(l, 16);
    l += __shfl_xor(l, 32);
    float* lf = (float*)(&Ks[0][w * 64]);
    lf[m16] = l;
    float linv[4];
#pragma unroll
    for (int r = 0; r < 4; r++) linv[r] = 1.0f / lf[quad * 4 + r];
#pragma unroll
    for (int r = 0; r < 4; r++) {
      const int row = qt * 128 + w * 32 + g * 16 + quad * 4 + r;
      ushort* crow = ctx + (bbase + row) * 1024 + h * 128;
#pragma unroll
      for (int dt = 0; dt < 8; dt++)
        crow[dt * 16 + m16] = f2bf(Oacc[g][dt][r] * linv[r]);
    }
  }
}

extern "C" void kernel_launch(void* const* d_in, const int* in_sizes, int n_in,
                              void* d_out, int out_size, void* d_ws, size_t ws_size,
                              hipStream_t stream) {
  const float* X  = (const float*)d_in[0];
  const float* Wi = (const float*)d_in[1];
  const float* bi = (const float*)d_in[2];
  const float* Wo = (const float*)d_in[3];
  const float* bo = (const float*)d_in[4];
  const float* Wd = (const float*)d_in[5];
  const float* bd = (const float*)d_in[6];
  float* out = (float*)d_out;

  ushort* p    = (ushort*)d_ws;
  ushort* Xb   = p; p += (size_t)8192 * 1024;   // 16.8MB; ctx reuses (post-qkv)
  ushort* Wib  = p; p += (size_t)3072 * 1024;   //  6.3MB
  ushort* WoTb = p; p += (size_t)1024 * 1024;   //  2.1MB
  ushort* Wdb  = p; p += (size_t)1024 * 1024;   //  2.1MB
  ushort* qkv  = p; p += (size_t)8192 * 3072;   // 50.3MB (V cols unused now)
  ushort* Vt   = p; p += (size_t)4096 * 2048;   // 16.8MB
  float*  bc   = (float*)p; p += 2048;          //  4KB   -> 94.38MB
  ushort* WcbSep = p; p += (size_t)1024 * 1024; //  2.1MB (merged mode only)
  const size_t need_merged = (size_t)((char*)p - (char*)d_ws);
  const bool merged = ws_size >= need_merged;

  ushort* ctx = Xb;                     // free after qkv GEMM consumed Xb
  ushort* Wcb = merged ? WcbSep : Wib;  // fallback: alias (separate launch)

  cvt_all<<<6144, 256, 0, stream>>>(X, Wi, Wd, Xb, Wib, Wdb);
  cvtT<<<dim3(16, 16), 256, 0, stream>>>(Wo, WoTb);
  bck<<<1024, 64, 0, stream>>>(Wd, bo, bd, bc, out);
  if (merged) {
    gemm_qkv<<<1600, 256, 0, stream>>>(Xb, Wib, bi, qkv, Vt, Wdb, WoTb, Wcb);
  } else {
    gemm_qkv<<<1536, 256, 0, stream>>>(Xb, Wib, bi, qkv, Vt, Wdb, WoTb, nullptr);
    gemm_bt<true><<<dim3(8, 8), 256, 0, stream>>>(Wdb, WoTb, nullptr, Wcb,
                                                  1024, 1024, 1024);
  }
  attn<<<dim3(16, 8, 4), 256, 0, stream>>>(qkv, Vt, ctx);
  gemm_bt<false><<<dim3(8, 64), 256, 0, stream>>>(ctx, Wcb, bc, out + 4, 8192, 1024, 1024);
}